// Round 12
// baseline (1330.771 us; speedup 1.0000x reference)
//
#include <hip/hip_runtime.h>

#define Bsz 512
#define Tsz 64
#define Hsz 512

typedef __attribute__((ext_vector_type(8))) short bf16x8;
typedef __attribute__((ext_vector_type(4))) float f32x4;

__device__ __forceinline__ unsigned short f2bf(float f) {
  union { float f; unsigned int u; } a; a.f = f;
  unsigned int u = a.u;
  unsigned int lsb = (u >> 16) & 1;
  u += 0x7fffu + lsb;   // round-to-nearest-even
  return (unsigned short)(u >> 16);
}

__device__ __forceinline__ void gload16(const void* g, void* l) {
  __builtin_amdgcn_global_load_lds(
      (const __attribute__((address_space(1))) unsigned int*)g,
      (__attribute__((address_space(3))) unsigned int*)l, 16, 0, 0);
}

__device__ __forceinline__ float sigm(float x) { return 1.f / (1.f + __expf(-x)); }
__device__ __forceinline__ float tanh_f(float x) { return 2.f / (1.f + __expf(-2.f * x)) - 1.f; }

// ---------------- converts (unchanged) ----------------
__global__ __launch_bounds__(256) void k_conv_x(const float* __restrict__ x,
                                                unsigned short* __restrict__ xbf) {
  int v = blockIdx.x * 256 + threadIdx.x;
  int e = v * 8;
  int i = e & 511;
  int t = (e >> 9) & 63;
  int b = e >> 15;
  float4 f0 = *(const float4*)(x + e);
  float4 f1 = *(const float4*)(x + e + 4);
  bf16x8 o;
  o[0] = (short)f2bf(f0.x); o[1] = (short)f2bf(f0.y);
  o[2] = (short)f2bf(f0.z); o[3] = (short)f2bf(f0.w);
  o[4] = (short)f2bf(f1.x); o[5] = (short)f2bf(f1.y);
  o[6] = (short)f2bf(f1.z); o[7] = (short)f2bf(f1.w);
  *(bf16x8*)(xbf + ((size_t)(t * 512 + b) << 9) + i) = o;
}

__global__ __launch_bounds__(256) void k_conv_w(
    const float* __restrict__ wihf, const float* __restrict__ whhf,
    const float* __restrict__ wihb, const float* __restrict__ whhb,
    const float* __restrict__ wlin,
    unsigned short* __restrict__ Wcat, unsigned short* __restrict__ wlinbf) {
  int v = blockIdx.x * 256 + threadIdx.x;
  const int nW = 2 * 16 * 128 * 128;
  if (v < nW) {
    int k8 = v & 127; int row = v >> 7;
    int c = row & 127, sl = (row >> 7) & 15, d = row >> 11;
    int g = c >> 5, hl = c & 31;
    int wr = g * 512 + sl * 32 + hl;
    int k = k8 * 8;
    const float* src;
    if (k < 512) src = (d ? wihb : wihf) + (size_t)wr * 512 + k;
    else         src = (d ? whhb : whhf) + (size_t)wr * 512 + (k - 512);
    float4 f0 = *(const float4*)src;
    float4 f1 = *(const float4*)(src + 4);
    bf16x8 o;
    o[0] = (short)f2bf(f0.x); o[1] = (short)f2bf(f0.y);
    o[2] = (short)f2bf(f0.z); o[3] = (short)f2bf(f0.w);
    o[4] = (short)f2bf(f1.x); o[5] = (short)f2bf(f1.y);
    o[6] = (short)f2bf(f1.z); o[7] = (short)f2bf(f1.w);
    *(bf16x8*)(Wcat + (size_t)row * 1024 + k) = o;
  } else {
    int v2 = v - nW;
    const float* src = wlin + (size_t)v2 * 8;
    float4 f0 = *(const float4*)src;
    float4 f1 = *(const float4*)(src + 4);
    bf16x8 o;
    o[0] = (short)f2bf(f0.x); o[1] = (short)f2bf(f0.y);
    o[2] = (short)f2bf(f0.z); o[3] = (short)f2bf(f0.w);
    o[4] = (short)f2bf(f1.x); o[5] = (short)f2bf(f1.y);
    o[6] = (short)f2bf(f1.z); o[7] = (short)f2bf(f1.w);
    *(bf16x8*)(wlinbf + (size_t)v2 * 8) = o;
  }
}

// ---------------- LSTM step: reg-double-buffered A (2-chunk lead), LDS = W only ----------------
// grid 256 (1 block/CU), 512 thr (8 waves 2x4, 32x32 acc). Tile [64 b x 128 c], K=1024, BK=64.
// LDS: 5 x B-buf[128][64] 16KB = 80KB; sD f32[64][128] (32KB) reuses bufs after the loop.
// Per iter: STAGE B(m+3) [2 gload_lds]; counted wait; barrier; MFMA(aBank[m&1], B(m));
// LOADA(m+2) -> aBank[m&1]. vmcnt schedule (issue-order derived): 6,10,8...8,6,4,0.
__global__ __launch_bounds__(512) void k_step(
    const unsigned short* __restrict__ xf, const unsigned short* __restrict__ xb,
    const unsigned short* __restrict__ hpf, const unsigned short* __restrict__ hpb,
    const unsigned short* __restrict__ Wcat,
    const float* __restrict__ biasf, const float* __restrict__ biasb,
    float* __restrict__ c_all,
    unsigned short* __restrict__ hof, unsigned short* __restrict__ hob) {
  extern __shared__ char smem[];
  const int tid = threadIdx.x;
  const int g32 = blockIdx.x & 31;
  const int mt  = blockIdx.x >> 5;
  const int dir = g32 & 1;
  const int sl  = g32 >> 1;
  const int b0  = mt * 64;

  const unsigned short* xd = dir ? xb : xf;
  const unsigned short* hd = dir ? hpb : hpf;
  const unsigned short* Wd = Wcat + (size_t)(dir * 16 + sl) * (128 * 1024);
  const float* bias = dir ? biasb : biasf;
  float* cd = c_all + (size_t)dir * (Bsz * Hsz);
  unsigned short* hod = dir ? hob : hof;

  const int lane = tid & 63;
  const int wv = tid >> 6;               // 0..7
  const int wr = wv >> 2, wc = wv & 3;   // 2 x 4 waves
  const int l15 = lane & 15, l4 = lane >> 4;

  // earliest loads (oldest in vmcnt order, drained by first counted wait)
  const int hl = tid & 31;
  const int r0 = tid >> 5;               // 0..15
  const int hcg = sl * 32 + hl;
  float cv[4];
#pragma unroll
  for (int ii = 0; ii < 4; ++ii)
    cv[ii] = cd[(size_t)(b0 + r0 + ii * 16) * Hsz + hcg];
  const float bi = bias[hcg], bff = bias[512 + hcg], bg = bias[1024 + hcg], bo = bias[1536 + hcg];

  const f32x4 z4 = {0.f, 0.f, 0.f, 0.f};
  f32x4 acc[2][2];
#pragma unroll
  for (int i = 0; i < 2; ++i)
#pragma unroll
    for (int j = 0; j < 2; ++j) acc[i][j] = z4;

  // per-thread A base: rows (b0 + wr*32 + mi*16 + l15), 16B at elem offset (ks*4+l4)*8
  const unsigned short* a0x = xd + (size_t)(b0 + wr * 32 + l15) * 512 + l4 * 8;
  const unsigned short* a0h = hd + (size_t)(b0 + wr * 32 + l15) * 512 + l4 * 8;

  bf16x8 aP[2][2], aQ[2][2];   // [ks][mi], two named banks (static indexing only)

#define LOADA(kc, abank)                                                          \
  {                                                                               \
    const unsigned short* ab_ = ((kc) < 8) ? a0x : a0h;                           \
    const int ko_ = ((kc) & 7) * 64;                                              \
    _Pragma("unroll")                                                             \
    for (int ks_ = 0; ks_ < 2; ++ks_)                                             \
      _Pragma("unroll")                                                           \
      for (int mi_ = 0; mi_ < 2; ++mi_)                                           \
        abank[ks_][mi_] = *(const bf16x8*)(ab_ + (size_t)(mi_ * 16) * 512 + ko_ + ks_ * 32); \
  }

  // stage chunk kc of B (W) only: 2 gload16/thread
  auto STAGE = [&](int kc, char* buf) {
#pragma unroll
    for (int it = 0; it < 2; ++it) {
      int idx = it * 512 + tid;
      int row = idx >> 3, g = idx & 7;           // 128 rows x 8 groups of 16B
      int sc = g ^ (row & 7);
      gload16(Wd + (size_t)row * 1024 + kc * 64 + sc * 8, buf + idx * 16);
    }
  };

  // MFMA for one chunk from bank + LDS buffer
#define DOMFMA(abank, cur)                                                        \
  {                                                                               \
    _Pragma("unroll")                                                             \
    for (int ks_ = 0; ks_ < 2; ++ks_) {                                           \
      bf16x8 b_[2];                                                               \
      int sb_ = ks_ * 4 + l4;                                                     \
      _Pragma("unroll")                                                           \
      for (int ni_ = 0; ni_ < 2; ++ni_) {                                         \
        int row_ = wc * 32 + ni_ * 16 + l15;                                      \
        b_[ni_] = *(const bf16x8*)((cur) + row_ * 128 + (sb_ ^ (row_ & 7)) * 16); \
      }                                                                           \
      _Pragma("unroll")                                                           \
      for (int mi_ = 0; mi_ < 2; ++mi_)                                           \
        _Pragma("unroll")                                                         \
        for (int ni_ = 0; ni_ < 2; ++ni_)                                         \
          acc[mi_][ni_] = __builtin_amdgcn_mfma_f32_16x16x32_bf16(abank[ks_][mi_], b_[ni_], acc[mi_][ni_], 0, 0, 0); \
    }                                                                             \
  }

  // prologue (issue order matters): A0, A1, B0, B1, B2
  LOADA(0, aP);
  LOADA(1, aQ);
  STAGE(0, smem);
  STAGE(1, smem + 16384);
  STAGE(2, smem + 32768);

#pragma unroll
  for (int mm = 0; mm < 8; ++mm) {
    const int m0 = 2 * mm, m1 = 2 * mm + 1;
    // ---- even chunk m0 (bank aP) ----
    {
      char* cur = smem + (m0 % 5) * 16384;
      if (m0 + 3 <= 15) STAGE(m0 + 3, smem + ((m0 + 3) % 5) * 16384);
      if (m0 == 0)       asm volatile("s_waitcnt vmcnt(6)" ::: "memory");
      else if (m0 == 14) asm volatile("s_waitcnt vmcnt(4)" ::: "memory");
      else               asm volatile("s_waitcnt vmcnt(8)" ::: "memory");
      __builtin_amdgcn_s_barrier();
      DOMFMA(aP, cur);
      if (m0 + 2 <= 15) LOADA(m0 + 2, aP);
    }
    // ---- odd chunk m1 (bank aQ) ----
    {
      char* cur = smem + (m1 % 5) * 16384;
      if (m1 + 3 <= 15) STAGE(m1 + 3, smem + ((m1 + 3) % 5) * 16384);
      if (m1 == 1)       asm volatile("s_waitcnt vmcnt(10)" ::: "memory");
      else if (m1 == 13) asm volatile("s_waitcnt vmcnt(6)" ::: "memory");
      else if (m1 == 15) asm volatile("s_waitcnt vmcnt(0)" ::: "memory");
      else               asm volatile("s_waitcnt vmcnt(8)" ::: "memory");
      __builtin_amdgcn_s_barrier();
      DOMFMA(aQ, cur);
      if (m1 + 2 <= 15) LOADA(m1 + 2, aQ);
    }
  }
  __syncthreads();

  // dump acc -> sD [64][128] f32, bank-swizzled: col ^= ((row>>2)&3)<<4
  float* sD = (float*)smem;
#pragma unroll
  for (int mi = 0; mi < 2; ++mi)
#pragma unroll
    for (int ni = 0; ni < 2; ++ni) {
      int rowb = wr * 32 + mi * 16 + l4 * 4;
      int col = wc * 32 + ni * 16 + l15;
#pragma unroll
      for (int r = 0; r < 4; ++r) {
        int rr = rowb + r;
        sD[rr * 128 + (col ^ (((rr >> 2) & 3) << 4))] = acc[mi][ni][r];
      }
    }
  __syncthreads();

#pragma unroll
  for (int ii = 0; ii < 4; ++ii) {
    int row = r0 + ii * 16;
    int sw = ((row >> 2) & 3) << 4;
    float iv = sD[row * 128 + ((0  + hl) ^ sw)] + bi;
    float fv = sD[row * 128 + ((32 + hl) ^ sw)] + bff;
    float gv = sD[row * 128 + ((64 + hl) ^ sw)] + bg;
    float ov = sD[row * 128 + ((96 + hl) ^ sw)] + bo;
    float ig = sigm(iv);
    float fg = sigm(fv);
    float gg = tanh_f(gv);
    float og = sigm(ov);
    size_t gi = (size_t)(b0 + row) * Hsz + hcg;
    float cn = fg * cv[ii] + ig * gg;
    cd[gi] = cn;
    hod[gi] = f2bf(og * tanh_f(cn));
  }
#undef LOADA
#undef DOMFMA
}

// ---------------- output GEMM: XCD-swizzled (unchanged) ----------------
__global__ __launch_bounds__(256) void k_out(
    const unsigned short* __restrict__ hsf, const unsigned short* __restrict__ hsb,
    const unsigned short* __restrict__ wlin, const float* __restrict__ blin,
    float* __restrict__ out) {
  extern __shared__ char smem[];
  const int tid = threadIdx.x;
  const int bidx = blockIdx.x;
  const int mt = (bidx & 7) + 8 * (bidx >> 5);
  const int nt = (bidx >> 3) & 3;
  const int m0 = mt * 128, n0 = nt * 128;
  const int lane = tid & 63, wv = tid >> 6;
  const int wr = wv >> 1, wc = wv & 1;
  const int l15 = lane & 15, l4 = lane >> 4;

  const f32x4 z4 = {0.f, 0.f, 0.f, 0.f};
  f32x4 acc[4][4];
#pragma unroll
  for (int i = 0; i < 4; ++i)
#pragma unroll
    for (int j = 0; j < 4; ++j) acc[i][j] = z4;

  for (int kc = 0; kc < 16; ++kc) {
    if (kc) __syncthreads();
    const unsigned short* Asrc = (kc < 8) ? hsf : hsb;
    const int kk = (kc & 7) * 64;
#pragma unroll
    for (int it = 0; it < 4; ++it) {
      int idx = it * 256 + tid;
      int row = idx >> 3, c16 = idx & 7;
      int sc = c16 ^ (row & 7);
      gload16(Asrc + (size_t)(m0 + row) * 512 + kk + sc * 8, smem + idx * 16);
    }
#pragma unroll
    for (int it = 0; it < 4; ++it) {
      int idx = it * 256 + tid;
      int row = idx >> 3, c16 = idx & 7;
      int sc = c16 ^ (row & 7);
      gload16(wlin + (size_t)(n0 + row) * 1024 + kc * 64 + sc * 8, smem + 16384 + idx * 16);
    }
    __syncthreads();
#pragma unroll
    for (int ks = 0; ks < 2; ++ks) {
      bf16x8 a[4], b[4];
      int sb = ks * 4 + l4;
#pragma unroll
      for (int mi = 0; mi < 4; ++mi) {
        int row = wr * 64 + mi * 16 + l15;
        a[mi] = *(const bf16x8*)(smem + row * 128 + (sb ^ (row & 7)) * 16);
      }
#pragma unroll
      for (int ni = 0; ni < 4; ++ni) {
        int row = wc * 64 + ni * 16 + l15;
        b[ni] = *(const bf16x8*)(smem + 16384 + row * 128 + (sb ^ (row & 7)) * 16);
      }
#pragma unroll
      for (int mi = 0; mi < 4; ++mi)
#pragma unroll
        for (int ni = 0; ni < 4; ++ni)
          acc[mi][ni] = __builtin_amdgcn_mfma_f32_16x16x32_bf16(a[mi], b[ni], acc[mi][ni], 0, 0, 0);
    }
  }
#pragma unroll
  for (int mi = 0; mi < 4; ++mi)
#pragma unroll
    for (int ni = 0; ni < 4; ++ni) {
      int cc = n0 + wc * 64 + ni * 16 + l15;
      float bl = blin[cc];
#pragma unroll
      for (int r = 0; r < 4; ++r) {
        int rr = m0 + wr * 64 + mi * 16 + l4 * 4 + r;
        int b = rr & 511, t = rr >> 9;
        out[(size_t)(b * 64 + t) * 512 + cc] = acc[mi][ni][r] + bl;
      }
    }
}

extern "C" void kernel_launch(void* const* d_in, const int* in_sizes, int n_in,
                              void* d_out, int out_size, void* d_ws, size_t ws_size,
                              hipStream_t stream) {
  const float* x     = (const float*)d_in[0];
  const float* wih_f = (const float*)d_in[1];
  const float* whh_f = (const float*)d_in[2];
  const float* b_f   = (const float*)d_in[3];
  const float* wih_b = (const float*)d_in[4];
  const float* whh_b = (const float*)d_in[5];
  const float* b_b   = (const float*)d_in[6];
  const float* wlin  = (const float*)d_in[7];
  const float* blin  = (const float*)d_in[8];
  float* out = (float*)d_out;

  char* ws = (char*)d_ws;
  unsigned short* Wcat   = (unsigned short*)(ws + 0);
  unsigned short* wlinbf = (unsigned short*)(ws + 8388608);
  unsigned short* xbf    = (unsigned short*)(ws + 9437184);
  unsigned short* hsf    = (unsigned short*)(ws + 42991616);
  unsigned short* hsb    = (unsigned short*)(ws + 76546048);
  float*          c_all  = (float*)(ws + 110100480);
  unsigned short* h0     = (unsigned short*)(ws + 112197632);

  hipMemsetAsync(c_all, 0, 2097152, stream);
  hipMemsetAsync(h0, 0, 524288, stream);
  k_conv_x<<<8192, 256, 0, stream>>>(x, xbf);
  k_conv_w<<<2304, 256, 0, stream>>>(wih_f, whh_f, wih_b, whh_b, wlin, Wcat, wlinbf);

  const size_t BH = (size_t)Bsz * Hsz;
  for (int s = 0; s < 64; ++s) {
    int tf = s, tb = 63 - s;
    const unsigned short* xfp = xbf + (size_t)tf * BH;
    const unsigned short* xbp = xbf + (size_t)tb * BH;
    const unsigned short* hpf = s ? hsf + (size_t)(tf - 1) * BH : h0;
    const unsigned short* hpb = s ? hsb + (size_t)(tb + 1) * BH : h0;
    k_step<<<256, 512, 81920, stream>>>(xfp, xbp, hpf, hpb, Wcat, b_f, b_b,
                                        c_all, hsf + (size_t)tf * BH, hsb + (size_t)tb * BH);
  }
  k_out<<<1024, 256, 32768, stream>>>(hsf, hsb, wlinbf, blin, out);
}

// Round 13
// 761.100 us; speedup vs baseline: 1.7485x; 1.7485x over previous
//
#include <hip/hip_runtime.h>

#define Bsz 512
#define Tsz 64
#define Hsz 512

typedef __attribute__((ext_vector_type(8))) short bf16x8;
typedef __attribute__((ext_vector_type(4))) float f32x4;
typedef __attribute__((ext_vector_type(4))) unsigned short u16x4;

__device__ __forceinline__ unsigned short f2bf(float f) {
  union { float f; unsigned int u; } a; a.f = f;
  unsigned int u = a.u;
  unsigned int lsb = (u >> 16) & 1;
  u += 0x7fffu + lsb;   // round-to-nearest-even
  return (unsigned short)(u >> 16);
}

__device__ __forceinline__ float bf2f(unsigned short u) {
  union { float f; unsigned int u; } a; a.u = ((unsigned int)u) << 16; return a.f;
}

__device__ __forceinline__ void gload16(const void* g, void* l) {
  __builtin_amdgcn_global_load_lds(
      (const __attribute__((address_space(1))) unsigned int*)g,
      (__attribute__((address_space(3))) unsigned int*)l, 16, 0, 0);
}

__device__ __forceinline__ float sigm(float x) { return 1.f / (1.f + __expf(-x)); }
__device__ __forceinline__ float tanh_f(float x) { return 2.f / (1.f + __expf(-2.f * x)) - 1.f; }

// ---------------- converts (unchanged) ----------------
__global__ __launch_bounds__(256) void k_conv_x(const float* __restrict__ x,
                                                unsigned short* __restrict__ xbf) {
  int v = blockIdx.x * 256 + threadIdx.x;
  int e = v * 8;
  int i = e & 511;
  int t = (e >> 9) & 63;
  int b = e >> 15;
  float4 f0 = *(const float4*)(x + e);
  float4 f1 = *(const float4*)(x + e + 4);
  bf16x8 o;
  o[0] = (short)f2bf(f0.x); o[1] = (short)f2bf(f0.y);
  o[2] = (short)f2bf(f0.z); o[3] = (short)f2bf(f0.w);
  o[4] = (short)f2bf(f1.x); o[5] = (short)f2bf(f1.y);
  o[6] = (short)f2bf(f1.z); o[7] = (short)f2bf(f1.w);
  *(bf16x8*)(xbf + ((size_t)(t * 512 + b) << 9) + i) = o;
}

__global__ __launch_bounds__(256) void k_conv_w(
    const float* __restrict__ wihf, const float* __restrict__ whhf,
    const float* __restrict__ wihb, const float* __restrict__ whhb,
    const float* __restrict__ wlin,
    unsigned short* __restrict__ Wcat, unsigned short* __restrict__ wlinbf) {
  int v = blockIdx.x * 256 + threadIdx.x;
  const int nW = 2 * 16 * 128 * 128;
  if (v < nW) {
    int k8 = v & 127; int row = v >> 7;
    int c = row & 127, sl = (row >> 7) & 15, d = row >> 11;
    int g = c >> 5, hl = c & 31;
    int wr = g * 512 + sl * 32 + hl;
    int k = k8 * 8;
    const float* src;
    if (k < 512) src = (d ? wihb : wihf) + (size_t)wr * 512 + k;
    else         src = (d ? whhb : whhf) + (size_t)wr * 512 + (k - 512);
    float4 f0 = *(const float4*)src;
    float4 f1 = *(const float4*)(src + 4);
    bf16x8 o;
    o[0] = (short)f2bf(f0.x); o[1] = (short)f2bf(f0.y);
    o[2] = (short)f2bf(f0.z); o[3] = (short)f2bf(f0.w);
    o[4] = (short)f2bf(f1.x); o[5] = (short)f2bf(f1.y);
    o[6] = (short)f2bf(f1.z); o[7] = (short)f2bf(f1.w);
    *(bf16x8*)(Wcat + (size_t)row * 1024 + k) = o;
  } else {
    int v2 = v - nW;
    const float* src = wlin + (size_t)v2 * 8;
    float4 f0 = *(const float4*)src;
    float4 f1 = *(const float4*)(src + 4);
    bf16x8 o;
    o[0] = (short)f2bf(f0.x); o[1] = (short)f2bf(f0.y);
    o[2] = (short)f2bf(f0.z); o[3] = (short)f2bf(f0.w);
    o[4] = (short)f2bf(f1.x); o[5] = (short)f2bf(f1.y);
    o[6] = (short)f2bf(f1.z); o[7] = (short)f2bf(f1.w);
    *(bf16x8*)(wlinbf + (size_t)v2 * 8) = o;
  }
}

// ---------------- gx GEMM: gx[st] = W_ih @ x[t]^T for 4 steps, LDS-tiled (k_out clone) ----------
// grid 512: xcd=bid&7, q=bid>>3: btile=q&3, pair=(q>>2)&3, t4=q>>4. g32=xcd+8*pair ->
// mtile=(g32&1)*16+(g32>>1) (XCD matches k_step's W slice home). Tile [128 m][128 b], K=512.
// gxring: [slot 8][m 4096][b 512] bf16, m = (dir*16+sl)*128 + gatecol.
__global__ __launch_bounds__(256) void k_gx(int base,
    const unsigned short* __restrict__ xbf, const unsigned short* __restrict__ Wcat,
    unsigned short* __restrict__ gxring) {
  extern __shared__ char smem[];
  const int tid = threadIdx.x;
  const int bid = blockIdx.x;
  const int xcd = bid & 7;
  const int q = bid >> 3;
  const int btile = q & 3;
  const int pair = (q >> 2) & 3;
  const int t4 = q >> 4;
  const int g32 = xcd + 8 * pair;
  const int mtile = (g32 & 1) * 16 + (g32 >> 1);
  const int m0 = mtile * 128, b0 = btile * 128;
  const int st = base + t4;
  const int slot = st & 7;
  const int dir = g32 & 1;
  const int t = dir ? (63 - st) : st;

  const unsigned short* Asrc = Wcat + (size_t)m0 * 1024;             // rows m, k<512 (ih half)
  const unsigned short* Bsrc = xbf + ((size_t)(t * 512 + b0) << 9);  // rows b, k<512

  const int lane = tid & 63, wv = tid >> 6;
  const int wr = wv >> 1, wc = wv & 1;
  const int l15 = lane & 15, l4 = lane >> 4;

  const f32x4 z4 = {0.f, 0.f, 0.f, 0.f};
  f32x4 acc[4][4];
#pragma unroll
  for (int i = 0; i < 4; ++i)
#pragma unroll
    for (int j = 0; j < 4; ++j) acc[i][j] = z4;

  for (int kc = 0; kc < 8; ++kc) {
    if (kc) __syncthreads();
#pragma unroll
    for (int it = 0; it < 4; ++it) {
      int idx = it * 256 + tid;
      int row = idx >> 3, c16 = idx & 7;
      int sc = c16 ^ (row & 7);
      gload16(Asrc + (size_t)row * 1024 + kc * 64 + sc * 8, smem + idx * 16);
    }
#pragma unroll
    for (int it = 0; it < 4; ++it) {
      int idx = it * 256 + tid;
      int row = idx >> 3, c16 = idx & 7;
      int sc = c16 ^ (row & 7);
      gload16(Bsrc + ((size_t)row << 9) + kc * 64 + sc * 8, smem + 16384 + idx * 16);
    }
    __syncthreads();
#pragma unroll
    for (int ks = 0; ks < 2; ++ks) {
      bf16x8 a[4], b[4];
      int sb = ks * 4 + l4;
#pragma unroll
      for (int mi = 0; mi < 4; ++mi) {
        int row = wr * 64 + mi * 16 + l15;
        a[mi] = *(const bf16x8*)(smem + row * 128 + (sb ^ (row & 7)) * 16);
      }
#pragma unroll
      for (int ni = 0; ni < 4; ++ni) {
        int row = wc * 64 + ni * 16 + l15;
        b[ni] = *(const bf16x8*)(smem + 16384 + row * 128 + (sb ^ (row & 7)) * 16);
      }
#pragma unroll
      for (int mi = 0; mi < 4; ++mi)
#pragma unroll
        for (int ni = 0; ni < 4; ++ni)
          acc[mi][ni] = __builtin_amdgcn_mfma_f32_16x16x32_bf16(a[mi], b[ni], acc[mi][ni], 0, 0, 0);
    }
  }
  unsigned short* go = gxring + (size_t)slot * (4096 * 512);
#pragma unroll
  for (int mi = 0; mi < 4; ++mi)
#pragma unroll
    for (int ni = 0; ni < 4; ++ni) {
      int bcol = b0 + wc * 64 + ni * 16 + l15;
#pragma unroll
      for (int r = 0; r < 4; ++r) {
        int m = m0 + wr * 64 + mi * 16 + l4 * 4 + r;
        go[(size_t)m * 512 + bcol] = f2bf(acc[mi][ni][r]);
      }
    }
}

// ---------------- LSTM step: h-part only (K=512), acc init from gxring (R9 skeleton) ----------
// grid 256 (1 block/CU), 512 thr (8 waves 2x4, 32x32 acc). Tile [64 b][128 c], 8 chunks BK=64.
// LDS: 5 bufs x 24KB (A[64][64] 8KB + B[128][64] 16KB) = 120KB; sD reuses base after loop.
__global__ __launch_bounds__(512) void k_step(
    const unsigned short* __restrict__ hpf, const unsigned short* __restrict__ hpb,
    const unsigned short* __restrict__ Wcat, const unsigned short* __restrict__ gx_s,
    const float* __restrict__ biasf, const float* __restrict__ biasb,
    float* __restrict__ c_all,
    unsigned short* __restrict__ hof, unsigned short* __restrict__ hob) {
  extern __shared__ char smem[];
  const int tid = threadIdx.x;
  const int g32 = blockIdx.x & 31;
  const int mt  = blockIdx.x >> 5;
  const int dir = g32 & 1;
  const int sl  = g32 >> 1;
  const int b0  = mt * 64;

  const unsigned short* hd = dir ? hpb : hpf;
  const unsigned short* Wd = Wcat + (size_t)(dir * 16 + sl) * (128 * 1024);
  const float* bias = dir ? biasb : biasf;
  float* cd = c_all + (size_t)dir * (Bsz * Hsz);
  unsigned short* hod = dir ? hob : hof;
  const unsigned short* gsrc = gx_s + (size_t)((dir * 16 + sl) * 128) * 512;

  const int lane = tid & 63;
  const int wv = tid >> 6;
  const int wr = wv >> 2, wc = wv & 3;   // 2 x 4 waves
  const int l15 = lane & 15, l4 = lane >> 4;

  // early global loads (oldest in vmcnt order): c, bias, gx fragments
  const int hl = tid & 31;
  const int r0 = tid >> 5;
  const int hcg = sl * 32 + hl;
  float cv[4];
#pragma unroll
  for (int ii = 0; ii < 4; ++ii)
    cv[ii] = cd[(size_t)(b0 + r0 + ii * 16) * Hsz + hcg];
  const float bi = bias[hcg], bff = bias[512 + hcg], bg = bias[1024 + hcg], bo = bias[1536 + hcg];

  u16x4 gvals[2][2];
#pragma unroll
  for (int mi = 0; mi < 2; ++mi)
#pragma unroll
    for (int ni = 0; ni < 2; ++ni)
      gvals[mi][ni] = *(const u16x4*)(gsrc + (size_t)(wc * 32 + ni * 16 + l15) * 512
                                      + b0 + wr * 32 + mi * 16 + l4 * 4);

  // stage chunk kc (h-part k = kc*64 .. +64): A 1 gload/thread, B 2 gloads/thread
  auto STAGE = [&](int kc, char* buf) {
    {
      int row = tid >> 3, g = tid & 7;           // 64 rows x 8 groups
      int sc = g ^ (row & 7);
      gload16(hd + (size_t)(b0 + row) * 512 + kc * 64 + sc * 8, buf + tid * 16);
    }
#pragma unroll
    for (int it = 0; it < 2; ++it) {
      int idx = it * 512 + tid;
      int row = idx >> 3, g = idx & 7;           // 128 rows x 8 groups
      int sc = g ^ (row & 7);
      gload16(Wd + (size_t)row * 1024 + 512 + kc * 64 + sc * 8, buf + 8192 + idx * 16);
    }
  };

  STAGE(0, smem);
  STAGE(1, smem + 24576);
  STAGE(2, smem + 49152);

  // init acc from gx (compiler waits the gvals here; STAGE 0-2 latency overlaps)
  f32x4 acc[2][2];
#pragma unroll
  for (int mi = 0; mi < 2; ++mi)
#pragma unroll
    for (int ni = 0; ni < 2; ++ni) {
      f32x4 a4 = {bf2f(gvals[mi][ni][0]), bf2f(gvals[mi][ni][1]),
                  bf2f(gvals[mi][ni][2]), bf2f(gvals[mi][ni][3])};
      acc[mi][ni] = a4;
    }

  for (int m = 0; m < 8; ++m) {
    char* cur = smem + (m % 5) * 24576;
    if (m < 5) {
      STAGE(m + 3, smem + ((m + 3) % 5) * 24576);
      asm volatile("s_waitcnt vmcnt(9)" ::: "memory");   // chunk m landed; m+1..m+3 in flight
    } else if (m == 5) {
      asm volatile("s_waitcnt vmcnt(6)" ::: "memory");
    } else if (m == 6) {
      asm volatile("s_waitcnt vmcnt(3)" ::: "memory");
    } else {
      asm volatile("s_waitcnt vmcnt(0)" ::: "memory");
    }
    __builtin_amdgcn_s_barrier();

#pragma unroll
    for (int ks = 0; ks < 2; ++ks) {
      bf16x8 a[2], b[2];
      int sb = ks * 4 + l4;
#pragma unroll
      for (int mi = 0; mi < 2; ++mi) {
        int row = wr * 32 + mi * 16 + l15;
        a[mi] = *(const bf16x8*)(cur + row * 128 + (sb ^ (row & 7)) * 16);
      }
#pragma unroll
      for (int ni = 0; ni < 2; ++ni) {
        int row = wc * 32 + ni * 16 + l15;
        b[ni] = *(const bf16x8*)(cur + 8192 + row * 128 + (sb ^ (row & 7)) * 16);
      }
#pragma unroll
      for (int mi = 0; mi < 2; ++mi)
#pragma unroll
        for (int ni = 0; ni < 2; ++ni)
          acc[mi][ni] = __builtin_amdgcn_mfma_f32_16x16x32_bf16(a[mi], b[ni], acc[mi][ni], 0, 0, 0);
    }
    // single barrier per chunk: buf[(m+3)%5] written at iter m was last read at iter m-2,
    // whose ds_reads are consumed before each wave passed barrier(m-1).
  }
  __syncthreads();

  // dump acc -> sD [64][128] f32, bank-swizzled: col ^= ((row>>2)&3)<<4
  float* sD = (float*)smem;
#pragma unroll
  for (int mi = 0; mi < 2; ++mi)
#pragma unroll
    for (int ni = 0; ni < 2; ++ni) {
      int rowb = wr * 32 + mi * 16 + l4 * 4;
      int col = wc * 32 + ni * 16 + l15;
#pragma unroll
      for (int r = 0; r < 4; ++r) {
        int rr = rowb + r;
        sD[rr * 128 + (col ^ (((rr >> 2) & 3) << 4))] = acc[mi][ni][r];
      }
    }
  __syncthreads();

#pragma unroll
  for (int ii = 0; ii < 4; ++ii) {
    int row = r0 + ii * 16;
    int sw = ((row >> 2) & 3) << 4;
    float iv = sD[row * 128 + ((0  + hl) ^ sw)] + bi;
    float fv = sD[row * 128 + ((32 + hl) ^ sw)] + bff;
    float gv = sD[row * 128 + ((64 + hl) ^ sw)] + bg;
    float ov = sD[row * 128 + ((96 + hl) ^ sw)] + bo;
    float ig = sigm(iv);
    float fg = sigm(fv);
    float gg = tanh_f(gv);
    float og = sigm(ov);
    size_t gi = (size_t)(b0 + row) * Hsz + hcg;
    float cn = fg * cv[ii] + ig * gg;
    cd[gi] = cn;
    hod[gi] = f2bf(og * tanh_f(cn));
  }
}

// ---------------- output GEMM: XCD-swizzled (unchanged) ----------------
__global__ __launch_bounds__(256) void k_out(
    const unsigned short* __restrict__ hsf, const unsigned short* __restrict__ hsb,
    const unsigned short* __restrict__ wlin, const float* __restrict__ blin,
    float* __restrict__ out) {
  extern __shared__ char smem[];
  const int tid = threadIdx.x;
  const int bidx = blockIdx.x;
  const int mt = (bidx & 7) + 8 * (bidx >> 5);
  const int nt = (bidx >> 3) & 3;
  const int m0 = mt * 128, n0 = nt * 128;
  const int lane = tid & 63, wv = tid >> 6;
  const int wr = wv >> 1, wc = wv & 1;
  const int l15 = lane & 15, l4 = lane >> 4;

  const f32x4 z4 = {0.f, 0.f, 0.f, 0.f};
  f32x4 acc[4][4];
#pragma unroll
  for (int i = 0; i < 4; ++i)
#pragma unroll
    for (int j = 0; j < 4; ++j) acc[i][j] = z4;

  for (int kc = 0; kc < 16; ++kc) {
    if (kc) __syncthreads();
    const unsigned short* Asrc = (kc < 8) ? hsf : hsb;
    const int kk = (kc & 7) * 64;
#pragma unroll
    for (int it = 0; it < 4; ++it) {
      int idx = it * 256 + tid;
      int row = idx >> 3, c16 = idx & 7;
      int sc = c16 ^ (row & 7);
      gload16(Asrc + (size_t)(m0 + row) * 512 + kk + sc * 8, smem + idx * 16);
    }
#pragma unroll
    for (int it = 0; it < 4; ++it) {
      int idx = it * 256 + tid;
      int row = idx >> 3, c16 = idx & 7;
      int sc = c16 ^ (row & 7);
      gload16(wlin + (size_t)(n0 + row) * 1024 + kc * 64 + sc * 8, smem + 16384 + idx * 16);
    }
    __syncthreads();
#pragma unroll
    for (int ks = 0; ks < 2; ++ks) {
      bf16x8 a[4], b[4];
      int sb = ks * 4 + l4;
#pragma unroll
      for (int mi = 0; mi < 4; ++mi) {
        int row = wr * 64 + mi * 16 + l15;
        a[mi] = *(const bf16x8*)(smem + row * 128 + (sb ^ (row & 7)) * 16);
      }
#pragma unroll
      for (int ni = 0; ni < 4; ++ni) {
        int row = wc * 64 + ni * 16 + l15;
        b[ni] = *(const bf16x8*)(smem + 16384 + row * 128 + (sb ^ (row & 7)) * 16);
      }
#pragma unroll
      for (int mi = 0; mi < 4; ++mi)
#pragma unroll
        for (int ni = 0; ni < 4; ++ni)
          acc[mi][ni] = __builtin_amdgcn_mfma_f32_16x16x32_bf16(a[mi], b[ni], acc[mi][ni], 0, 0, 0);
    }
  }
#pragma unroll
  for (int mi = 0; mi < 4; ++mi)
#pragma unroll
    for (int ni = 0; ni < 4; ++ni) {
      int cc = n0 + wc * 64 + ni * 16 + l15;
      float bl = blin[cc];
#pragma unroll
      for (int r = 0; r < 4; ++r) {
        int rr = m0 + wr * 64 + mi * 16 + l4 * 4 + r;
        int b = rr & 511, t = rr >> 9;
        out[(size_t)(b * 64 + t) * 512 + cc] = acc[mi][ni][r] + bl;
      }
    }
}

extern "C" void kernel_launch(void* const* d_in, const int* in_sizes, int n_in,
                              void* d_out, int out_size, void* d_ws, size_t ws_size,
                              hipStream_t stream) {
  const float* x     = (const float*)d_in[0];
  const float* wih_f = (const float*)d_in[1];
  const float* whh_f = (const float*)d_in[2];
  const float* b_f   = (const float*)d_in[3];
  const float* wih_b = (const float*)d_in[4];
  const float* whh_b = (const float*)d_in[5];
  const float* b_b   = (const float*)d_in[6];
  const float* wlin  = (const float*)d_in[7];
  const float* blin  = (const float*)d_in[8];
  float* out = (float*)d_out;

  char* ws = (char*)d_ws;
  unsigned short* Wcat   = (unsigned short*)(ws + 0);           // 8 MB
  unsigned short* wlinbf = (unsigned short*)(ws + 8388608);     // 1 MB
  unsigned short* xbf    = (unsigned short*)(ws + 9437184);     // 32 MB
  unsigned short* hsf    = (unsigned short*)(ws + 42991616);    // 32 MB
  unsigned short* hsb    = (unsigned short*)(ws + 76546048);    // 32 MB
  float*          c_all  = (float*)(ws + 110100480);            // 2 MB
  unsigned short* h0     = (unsigned short*)(ws + 112197632);   // 512 KB
  unsigned short* gxring = (unsigned short*)(ws + 112721920);   // 32 MB (8 slots x 4 MB)

  hipMemsetAsync(c_all, 0, 2097152, stream);
  hipMemsetAsync(h0, 0, 524288, stream);
  k_conv_x<<<8192, 256, 0, stream>>>(x, xbf);
  k_conv_w<<<2304, 256, 0, stream>>>(wih_f, whh_f, wih_b, whh_b, wlin, Wcat, wlinbf);
  k_gx<<<512, 256, 32768, stream>>>(0, xbf, Wcat, gxring);   // steps 0..3
  k_gx<<<512, 256, 32768, stream>>>(4, xbf, Wcat, gxring);   // steps 4..7

  const size_t BH = (size_t)Bsz * Hsz;
  for (int s = 0; s < 64; ++s) {
    int tf = s, tb = 63 - s;
    const unsigned short* hpf = s ? hsf + (size_t)(tf - 1) * BH : h0;
    const unsigned short* hpb = s ? hsb + (size_t)(tb + 1) * BH : h0;
    k_step<<<256, 512, 122880, stream>>>(hpf, hpb, Wcat,
                                         gxring + (size_t)(s & 7) * (4096 * 512),
                                         b_f, b_b, c_all,
                                         hsf + (size_t)tf * BH, hsb + (size_t)tb * BH);
    if ((s & 3) == 3 && s + 5 <= 63)
      k_gx<<<512, 256, 32768, stream>>>(s + 5, xbf, Wcat, gxring);  // steps s+5..s+8
  }
  k_out<<<1024, 256, 32768, stream>>>(hsf, hsb, wlinbf, blin, out);
}

// Round 14
// 625.107 us; speedup vs baseline: 2.1289x; 1.2176x over previous
//
#include <hip/hip_runtime.h>

#define Bsz 512
#define Tsz 64
#define Hsz 512

typedef __attribute__((ext_vector_type(8))) short bf16x8;
typedef __attribute__((ext_vector_type(4))) float f32x4;

__device__ __forceinline__ unsigned short f2bf(float f) {
  union { float f; unsigned int u; } a; a.f = f;
  unsigned int u = a.u;
  unsigned int lsb = (u >> 16) & 1;
  u += 0x7fffu + lsb;   // round-to-nearest-even
  return (unsigned short)(u >> 16);
}

__device__ __forceinline__ void gload16(const void* g, void* l) {
  __builtin_amdgcn_global_load_lds(
      (const __attribute__((address_space(1))) unsigned int*)g,
      (__attribute__((address_space(3))) unsigned int*)l, 16, 0, 0);
}

__device__ __forceinline__ float sigm(float x) { return 1.f / (1.f + __expf(-x)); }
__device__ __forceinline__ float tanh_f(float x) { return 2.f / (1.f + __expf(-2.f * x)) - 1.f; }

// ---------------- converts ----------------
__global__ __launch_bounds__(256) void k_conv_x(const float* __restrict__ x,
                                                unsigned short* __restrict__ xbf) {
  int v = blockIdx.x * 256 + threadIdx.x;
  int e = v * 8;
  int i = e & 511;
  int t = (e >> 9) & 63;
  int b = e >> 15;
  float4 f0 = *(const float4*)(x + e);
  float4 f1 = *(const float4*)(x + e + 4);
  bf16x8 o;
  o[0] = (short)f2bf(f0.x); o[1] = (short)f2bf(f0.y);
  o[2] = (short)f2bf(f0.z); o[3] = (short)f2bf(f0.w);
  o[4] = (short)f2bf(f1.x); o[5] = (short)f2bf(f1.y);
  o[6] = (short)f2bf(f1.z); o[7] = (short)f2bf(f1.w);
  *(bf16x8*)(xbf + ((size_t)(t * 512 + b) << 9) + i) = o;
}

__global__ __launch_bounds__(256) void k_conv_w(
    const float* __restrict__ wihf, const float* __restrict__ whhf,
    const float* __restrict__ wihb, const float* __restrict__ whhb,
    const float* __restrict__ wlin,
    unsigned short* __restrict__ Wcat, unsigned short* __restrict__ wlinbf) {
  int v = blockIdx.x * 256 + threadIdx.x;
  const int nW = 2 * 16 * 128 * 128;
  if (v < nW) {
    int k8 = v & 127; int row = v >> 7;
    int c = row & 127, sl = (row >> 7) & 15, d = row >> 11;
    int g = c >> 5, hl = c & 31;
    int wr = g * 512 + sl * 32 + hl;
    int k = k8 * 8;
    const float* src;
    if (k < 512) src = (d ? wihb : wihf) + (size_t)wr * 512 + k;
    else         src = (d ? whhb : whhf) + (size_t)wr * 512 + (k - 512);
    float4 f0 = *(const float4*)src;
    float4 f1 = *(const float4*)(src + 4);
    bf16x8 o;
    o[0] = (short)f2bf(f0.x); o[1] = (short)f2bf(f0.y);
    o[2] = (short)f2bf(f0.z); o[3] = (short)f2bf(f0.w);
    o[4] = (short)f2bf(f1.x); o[5] = (short)f2bf(f1.y);
    o[6] = (short)f2bf(f1.z); o[7] = (short)f2bf(f1.w);
    *(bf16x8*)(Wcat + (size_t)row * 1024 + k) = o;
  } else {
    int v2 = v - nW;
    const float* src = wlin + (size_t)v2 * 8;
    float4 f0 = *(const float4*)src;
    float4 f1 = *(const float4*)(src + 4);
    bf16x8 o;
    o[0] = (short)f2bf(f0.x); o[1] = (short)f2bf(f0.y);
    o[2] = (short)f2bf(f0.z); o[3] = (short)f2bf(f0.w);
    o[4] = (short)f2bf(f1.x); o[5] = (short)f2bf(f1.y);
    o[6] = (short)f2bf(f1.z); o[7] = (short)f2bf(f1.w);
    *(bf16x8*)(wlinbf + (size_t)v2 * 8) = o;
  }
}

// ---------------- LSTM step: 8 waves (2/SIMD TLP) — verified best (R9, 621 us) ----------------
// grid 256 (1 block/CU): blockIdx = mt*32 + sl*2 + dir; tile [64 batch][128 cols], K=1024,
// BK=64 (16 chunks). buf = A[64][64](8KB)+B[128][64](16KB)=24KB; 5 bufs=120KB; depth-3,
// counted vmcnt(9) (3 gload16/thread/STAGE at 512 threads). 8 waves as 2(wr)x4(wc), 32x32 acc.
// Epilogue sD f32[64][128]=32KB reuses buf0+. XCD map: bid%8 = cs%8 -> W slices L2-resident.
__global__ __launch_bounds__(512) void k_step(
    const unsigned short* __restrict__ xf, const unsigned short* __restrict__ xb,
    const unsigned short* __restrict__ hpf, const unsigned short* __restrict__ hpb,
    const unsigned short* __restrict__ Wcat,
    const float* __restrict__ biasf, const float* __restrict__ biasb,
    float* __restrict__ c_all,
    unsigned short* __restrict__ hof, unsigned short* __restrict__ hob) {
  extern __shared__ char smem[];
  const int tid = threadIdx.x;
  const int g32 = blockIdx.x & 31;
  const int mt  = blockIdx.x >> 5;
  const int dir = g32 & 1;
  const int sl  = g32 >> 1;
  const int b0  = mt * 64;

  const unsigned short* xd = dir ? xb : xf;
  const unsigned short* hd = dir ? hpb : hpf;
  const unsigned short* Wd = Wcat + (size_t)(dir * 16 + sl) * (128 * 1024);
  const float* bias = dir ? biasb : biasf;
  float* cd = c_all + (size_t)dir * (Bsz * Hsz);
  unsigned short* hod = dir ? hob : hof;

  const int lane = tid & 63;
  const int wv = tid >> 6;               // 0..7
  const int wr = wv >> 2, wc = wv & 3;   // 2 x 4
  const int l15 = lane & 15, l4 = lane >> 4;

  // early loads (oldest in vmcnt order; drained by the first counted wait)
  const int hl = tid & 31;
  const int r0 = tid >> 5;               // 0..15
  const int hcg = sl * 32 + hl;
  float cv[4];
#pragma unroll
  for (int ii = 0; ii < 4; ++ii)
    cv[ii] = cd[(size_t)(b0 + r0 + ii * 16) * Hsz + hcg];
  const float bi = bias[hcg], bff = bias[512 + hcg], bg = bias[1024 + hcg], bo = bias[1536 + hcg];

  const f32x4 z4 = {0.f, 0.f, 0.f, 0.f};
  f32x4 acc[2][2];
#pragma unroll
  for (int i = 0; i < 2; ++i)
#pragma unroll
    for (int j = 0; j < 2; ++j) acc[i][j] = z4;

  // stage chunk kc: A 1 gload/thread (512 chunks), B 2 gloads/thread (1024 chunks)
  auto STAGE = [&](int kc, char* buf) {
    const unsigned short* Asrc = (kc < 8) ? xd : hd;
    const int koff = (kc & 7) * 64;
    {
      int row = tid >> 3, g = tid & 7;           // 64 rows x 8 groups
      int sc = g ^ (row & 7);
      gload16(Asrc + (size_t)(b0 + row) * 512 + koff + sc * 8, buf + tid * 16);
    }
#pragma unroll
    for (int it = 0; it < 2; ++it) {
      int idx = it * 512 + tid;
      int row = idx >> 3, g = idx & 7;           // 128 rows x 8 groups
      int sc = g ^ (row & 7);
      gload16(Wd + (size_t)row * 1024 + kc * 64 + sc * 8, buf + 8192 + idx * 16);
    }
  };

  STAGE(0, smem);
  STAGE(1, smem + 24576);
  STAGE(2, smem + 49152);

  for (int m = 0; m < 16; ++m) {
    char* cur = smem + (m % 5) * 24576;
    if (m < 13) {
      STAGE(m + 3, smem + ((m + 3) % 5) * 24576);
      asm volatile("s_waitcnt vmcnt(9)" ::: "memory");   // chunk m landed; m+1..m+3 in flight
    } else if (m == 13) {
      asm volatile("s_waitcnt vmcnt(6)" ::: "memory");
    } else if (m == 14) {
      asm volatile("s_waitcnt vmcnt(3)" ::: "memory");
    } else {
      asm volatile("s_waitcnt vmcnt(0)" ::: "memory");
    }
    __builtin_amdgcn_s_barrier();

#pragma unroll
    for (int ks = 0; ks < 2; ++ks) {
      bf16x8 a[2], b[2];
      int sb = ks * 4 + l4;
#pragma unroll
      for (int mi = 0; mi < 2; ++mi) {
        int row = wr * 32 + mi * 16 + l15;
        a[mi] = *(const bf16x8*)(cur + row * 128 + (sb ^ (row & 7)) * 16);
      }
#pragma unroll
      for (int ni = 0; ni < 2; ++ni) {
        int row = wc * 32 + ni * 16 + l15;
        b[ni] = *(const bf16x8*)(cur + 8192 + row * 128 + (sb ^ (row & 7)) * 16);
      }
#pragma unroll
      for (int mi = 0; mi < 2; ++mi)
#pragma unroll
        for (int ni = 0; ni < 2; ++ni)
          acc[mi][ni] = __builtin_amdgcn_mfma_f32_16x16x32_bf16(a[mi], b[ni], acc[mi][ni], 0, 0, 0);
    }
    // single barrier per chunk: buf[(m+3)%5] written at iter m was last read at iter m-2,
    // and those reads are consumed before each wave passed barrier(m-1).
  }
  __syncthreads();

  // dump acc -> sD [64][128] f32, bank-swizzled: col ^= ((row>>2)&3)<<4
  float* sD = (float*)smem;
#pragma unroll
  for (int mi = 0; mi < 2; ++mi)
#pragma unroll
    for (int ni = 0; ni < 2; ++ni) {
      int rowb = wr * 32 + mi * 16 + l4 * 4;
      int col = wc * 32 + ni * 16 + l15;
#pragma unroll
      for (int r = 0; r < 4; ++r) {
        int rr = rowb + r;
        sD[rr * 128 + (col ^ (((rr >> 2) & 3) << 4))] = acc[mi][ni][r];
      }
    }
  __syncthreads();

#pragma unroll
  for (int ii = 0; ii < 4; ++ii) {
    int row = r0 + ii * 16;
    int sw = ((row >> 2) & 3) << 4;
    float iv = sD[row * 128 + ((0  + hl) ^ sw)] + bi;
    float fv = sD[row * 128 + ((32 + hl) ^ sw)] + bff;
    float gv = sD[row * 128 + ((64 + hl) ^ sw)] + bg;
    float ov = sD[row * 128 + ((96 + hl) ^ sw)] + bo;
    float ig = sigm(iv);
    float fg = sigm(fv);
    float gg = tanh_f(gv);
    float og = sigm(ov);
    size_t gi = (size_t)(b0 + row) * Hsz + hcg;
    float cn = fg * cv[ii] + ig * gg;
    cd[gi] = cn;
    hod[gi] = f2bf(og * tanh_f(cn));
  }
}

// ---------------- output GEMM: XCD-swizzled ----------------
__global__ __launch_bounds__(256) void k_out(
    const unsigned short* __restrict__ hsf, const unsigned short* __restrict__ hsb,
    const unsigned short* __restrict__ wlin, const float* __restrict__ blin,
    float* __restrict__ out) {
  extern __shared__ char smem[];
  const int tid = threadIdx.x;
  const int bidx = blockIdx.x;
  const int mt = (bidx & 7) + 8 * (bidx >> 5);
  const int nt = (bidx >> 3) & 3;
  const int m0 = mt * 128, n0 = nt * 128;
  const int lane = tid & 63, wv = tid >> 6;
  const int wr = wv >> 1, wc = wv & 1;
  const int l15 = lane & 15, l4 = lane >> 4;

  const f32x4 z4 = {0.f, 0.f, 0.f, 0.f};
  f32x4 acc[4][4];
#pragma unroll
  for (int i = 0; i < 4; ++i)
#pragma unroll
    for (int j = 0; j < 4; ++j) acc[i][j] = z4;

  for (int kc = 0; kc < 16; ++kc) {
    if (kc) __syncthreads();
    const unsigned short* Asrc = (kc < 8) ? hsf : hsb;
    const int kk = (kc & 7) * 64;
#pragma unroll
    for (int it = 0; it < 4; ++it) {
      int idx = it * 256 + tid;
      int row = idx >> 3, c16 = idx & 7;
      int sc = c16 ^ (row & 7);
      gload16(Asrc + (size_t)(m0 + row) * 512 + kk + sc * 8, smem + idx * 16);
    }
#pragma unroll
    for (int it = 0; it < 4; ++it) {
      int idx = it * 256 + tid;
      int row = idx >> 3, c16 = idx & 7;
      int sc = c16 ^ (row & 7);
      gload16(wlin + (size_t)(n0 + row) * 1024 + kc * 64 + sc * 8, smem + 16384 + idx * 16);
    }
    __syncthreads();
#pragma unroll
    for (int ks = 0; ks < 2; ++ks) {
      bf16x8 a[4], b[4];
      int sb = ks * 4 + l4;
#pragma unroll
      for (int mi = 0; mi < 4; ++mi) {
        int row = wr * 64 + mi * 16 + l15;
        a[mi] = *(const bf16x8*)(smem + row * 128 + (sb ^ (row & 7)) * 16);
      }
#pragma unroll
      for (int ni = 0; ni < 4; ++ni) {
        int row = wc * 64 + ni * 16 + l15;
        b[ni] = *(const bf16x8*)(smem + 16384 + row * 128 + (sb ^ (row & 7)) * 16);
      }
#pragma unroll
      for (int mi = 0; mi < 4; ++mi)
#pragma unroll
        for (int ni = 0; ni < 4; ++ni)
          acc[mi][ni] = __builtin_amdgcn_mfma_f32_16x16x32_bf16(a[mi], b[ni], acc[mi][ni], 0, 0, 0);
    }
  }
#pragma unroll
  for (int mi = 0; mi < 4; ++mi)
#pragma unroll
    for (int ni = 0; ni < 4; ++ni) {
      int cc = n0 + wc * 64 + ni * 16 + l15;
      float bl = blin[cc];
#pragma unroll
      for (int r = 0; r < 4; ++r) {
        int rr = m0 + wr * 64 + mi * 16 + l4 * 4 + r;
        int b = rr & 511, t = rr >> 9;
        out[(size_t)(b * 64 + t) * 512 + cc] = acc[mi][ni][r] + bl;
      }
    }
}

extern "C" void kernel_launch(void* const* d_in, const int* in_sizes, int n_in,
                              void* d_out, int out_size, void* d_ws, size_t ws_size,
                              hipStream_t stream) {
  const float* x     = (const float*)d_in[0];
  const float* wih_f = (const float*)d_in[1];
  const float* whh_f = (const float*)d_in[2];
  const float* b_f   = (const float*)d_in[3];
  const float* wih_b = (const float*)d_in[4];
  const float* whh_b = (const float*)d_in[5];
  const float* b_b   = (const float*)d_in[6];
  const float* wlin  = (const float*)d_in[7];
  const float* blin  = (const float*)d_in[8];
  float* out = (float*)d_out;

  char* ws = (char*)d_ws;
  unsigned short* Wcat   = (unsigned short*)(ws + 0);
  unsigned short* wlinbf = (unsigned short*)(ws + 8388608);
  unsigned short* xbf    = (unsigned short*)(ws + 9437184);
  unsigned short* hsf    = (unsigned short*)(ws + 42991616);
  unsigned short* hsb    = (unsigned short*)(ws + 76546048);
  float*          c_all  = (float*)(ws + 110100480);
  unsigned short* h0     = (unsigned short*)(ws + 112197632);

  hipMemsetAsync(c_all, 0, 2097152, stream);
  hipMemsetAsync(h0, 0, 524288, stream);
  k_conv_x<<<8192, 256, 0, stream>>>(x, xbf);
  k_conv_w<<<2304, 256, 0, stream>>>(wih_f, whh_f, wih_b, whh_b, wlin, Wcat, wlinbf);

  const size_t BH = (size_t)Bsz * Hsz;
  for (int s = 0; s < 64; ++s) {
    int tf = s, tb = 63 - s;
    const unsigned short* xfp = xbf + (size_t)tf * BH;
    const unsigned short* xbp = xbf + (size_t)tb * BH;
    const unsigned short* hpf = s ? hsf + (size_t)(tf - 1) * BH : h0;
    const unsigned short* hpb = s ? hsb + (size_t)(tb + 1) * BH : h0;
    k_step<<<256, 512, 122880, stream>>>(xfp, xbp, hpf, hpb, Wcat, b_f, b_b,
                                         c_all, hsf + (size_t)tf * BH, hsb + (size_t)tb * BH);
  }
  k_out<<<1024, 256, 32768, stream>>>(hsf, hsb, wlinbf, blin, out);
}